// Round 2
// 160.484 us; speedup vs baseline: 1.1272x; 1.1272x over previous
//
#include <hip/hip_runtime.h>

// SSIM loss, R7b: resubmission of R7 (previous bench was an infra failure —
// "MI355X container failed twice", no pytest/counters). Kernel re-audited:
// all global loads guarded+aligned, all LDS indices in-bounds, all MFMA pads
// zero-filled, no data-dependent control flow.
//
// R7 design: move both separable-conv passes onto the matrix pipe.
// R6 post-mortem: VALU-issue bound (VALUBusy 66%, MfmaUtil 0, HBM 13%,
// conflicts ~0) — ~110 MAC/px of Gaussian conv on the vector ALU while MFMA
// idles. R7:
//   h-conv: D1[48 h-rows][64 cols] = X[48][K<=96] * Gh[K][64]  (banded analytic B)
//   v-conv: D2[64 cols][32 rows]   = Ht[64][K=64] * Gv[K][32]  (banded analytic B)
// using v_mfma_f32_16x16x32_f16. X = 5 f16 quantity planes (a,b,a2,b2,ab) built
// from f32 global loads (products in f32, one f16 rounding). D1 fragments are
// transpose-stored (free: 4 row-contiguous halves/lane -> ds_write_b64) into
// Ht which ALIASES X (barrier-separated). f16 weight rounding compensated by
// rs = 1/sum(fl16(g))^2. SSIM map evaluated directly on D2 fragments.
// Layout facts used: C/D col=lane&15,row=(lane>>4)*4+reg (HW-verified); A-row/
// B-col = lane&15; k-element-order uncertainty cancels (A and B built with the
// same assumed map). All MFMA-read pads zero-filled (no 0*NaN).

typedef __attribute__((ext_vector_type(4))) float  f32x4;
typedef __fp16 f16;
typedef __attribute__((ext_vector_type(2))) __fp16 h2v;
typedef __attribute__((ext_vector_type(4))) __fp16 h4;
typedef __attribute__((ext_vector_type(8))) __fp16 h8;

constexpr int IMG_H = 512;
constexpr int IMG_W = 512;
constexpr int NBC   = 48;                  // B*C planes
constexpr int TW    = 64;                  // output tile width
constexpr int TH    = 32;                  // output tile height
constexpr int NBLKX = IMG_W / TW;          // 8
constexpr int NBLKY = IMG_H / TH;          // 16
constexpr int NBLK  = NBLKX * NBLKY * NBC; // 6144

constexpr int XP   = 104;                  // X pitch (halves): 52 dw, 2-way banks, 16B rows
constexpr int XR   = 48;                   // X rows (42 data + 6 zero pad)
constexpr int XQS  = XR * XP;              // 4992 halves per quantity plane
constexpr int HTP  = 72;                   // Ht pitch (halves): 36 dw, 2-way banks, 16B rows
constexpr int HTQS = 64 * HTP;             // 4608 halves per quantity plane
constexpr int SMEMH = 5 * XQS;             // 24960 halves = 49920 B (Ht: 5*4608=23040 aliases)
static_assert(5 * HTQS <= SMEMH, "Ht must fit in X union");

constexpr float C1 = 1.0e-4f;
constexpr float C2 = 9.0e-4f;

__device__ __forceinline__ float gcoef(int d) {          // normalized gaussian, d in [0,10]
    const float x = (float)(d - 5);
    return __expf(x * x * -0.22222222f) * 0.26601176f;   // 1/(2*1.5^2), 1/sum(exp)
}

// Banded weight B-fragment: element i of lane group (lane>>4) holds
// B[k = ks*32 + grp8 + i][n = implicit via off]; weight = g[k - off], 0 outside band.
__device__ __forceinline__ h8 bfrag(int ks, int grp8, int off) {
    h8 b;
#pragma unroll
    for (int i = 0; i < 8; ++i) {
        const int idx = ks * 32 + grp8 + i - off;
        b[i] = (f16)(((unsigned)idx <= 10u) ? gcoef(idx) : 0.f);
    }
    return b;
}

__global__ __launch_bounds__(64) void ssim_init(double* acc) {
    if (threadIdx.x == 0) acc[0] = 0.0;
}

__global__ __launch_bounds__(256, 3) void ssim_main(const float* __restrict__ sr,
                                                    const float* __restrict__ hr,
                                                    double* __restrict__ sink,
                                                    int mode) {
    __shared__ __align__(16) f16 smem[SMEMH];   // X[5][48][104]  /  Ht[5][64][72] (aliased)
    __shared__ float wsums[4];

    const int tid  = threadIdx.x;
    const int w    = tid >> 6;                  // wave id: h-pass N-tile / v-pass M-tile
    const int lane = tid & 63;
    const int l15  = lane & 15;
    const int grp8 = (lane >> 4) << 3;
    const int grp4 = (lane >> 4) << 2;

    // f16-rounded weight sum -> renormalization (two conv passes => squared)
    float s16 = 0.f;
#pragma unroll
    for (int d = 0; d <= 10; ++d) s16 += (float)(f16)gcoef(d);
    const float rs = 1.0f / (s16 * s16);

    const int bc  = blockIdx.z;
    const int gr0 = blockIdx.y * TH - 5;        // global row of h-row 0
    const int gc0 = blockIdx.x * TW - 8;        // global col of X col 0 (float4-aligned halo)
    const float* __restrict__ srp = sr + (size_t)bc * IMG_H * IMG_W;
    const float* __restrict__ hrp = hr + (size_t)bc * IMG_H * IMG_W;

    // ---- stage: X[5][48][104] f16 planes (a, b, a*a, b*b, a*b); zero halo/pad ----
    for (int i = tid; i < XR * 13; i += 256) {  // 624 tasks x 8 cols (2 float4 per image)
        const int r = i / 13, t8 = i - r * 13;
        const int gr = gr0 + r, gc = gc0 + t8 * 8;
        h8 va = {}, vb = {}, vaa = {}, vbb = {}, vab = {};
        if (r < 42 && t8 < 10 && (unsigned)gr < (unsigned)IMG_H && (unsigned)gc < (unsigned)IMG_W) {
            const float4* pa = (const float4*)&srp[(size_t)gr * IMG_W + gc];
            const float4* pb = (const float4*)&hrp[(size_t)gr * IMG_W + gc];
            const float4 a0 = pa[0], a1 = pa[1];
            const float4 b0 = pb[0], b1 = pb[1];
            union { h2v h2[4]; h8 v; } ua, ub, uaa, ubb, uab;
            ua.h2[0]  = __builtin_amdgcn_cvt_pkrtz(a0.x, a0.y);
            ua.h2[1]  = __builtin_amdgcn_cvt_pkrtz(a0.z, a0.w);
            ua.h2[2]  = __builtin_amdgcn_cvt_pkrtz(a1.x, a1.y);
            ua.h2[3]  = __builtin_amdgcn_cvt_pkrtz(a1.z, a1.w);
            ub.h2[0]  = __builtin_amdgcn_cvt_pkrtz(b0.x, b0.y);
            ub.h2[1]  = __builtin_amdgcn_cvt_pkrtz(b0.z, b0.w);
            ub.h2[2]  = __builtin_amdgcn_cvt_pkrtz(b1.x, b1.y);
            ub.h2[3]  = __builtin_amdgcn_cvt_pkrtz(b1.z, b1.w);
            uaa.h2[0] = __builtin_amdgcn_cvt_pkrtz(a0.x * a0.x, a0.y * a0.y);
            uaa.h2[1] = __builtin_amdgcn_cvt_pkrtz(a0.z * a0.z, a0.w * a0.w);
            uaa.h2[2] = __builtin_amdgcn_cvt_pkrtz(a1.x * a1.x, a1.y * a1.y);
            uaa.h2[3] = __builtin_amdgcn_cvt_pkrtz(a1.z * a1.z, a1.w * a1.w);
            ubb.h2[0] = __builtin_amdgcn_cvt_pkrtz(b0.x * b0.x, b0.y * b0.y);
            ubb.h2[1] = __builtin_amdgcn_cvt_pkrtz(b0.z * b0.z, b0.w * b0.w);
            ubb.h2[2] = __builtin_amdgcn_cvt_pkrtz(b1.x * b1.x, b1.y * b1.y);
            ubb.h2[3] = __builtin_amdgcn_cvt_pkrtz(b1.z * b1.z, b1.w * b1.w);
            uab.h2[0] = __builtin_amdgcn_cvt_pkrtz(a0.x * b0.x, a0.y * b0.y);
            uab.h2[1] = __builtin_amdgcn_cvt_pkrtz(a0.z * b0.z, a0.w * b0.w);
            uab.h2[2] = __builtin_amdgcn_cvt_pkrtz(a1.x * b1.x, a1.y * b1.y);
            uab.h2[3] = __builtin_amdgcn_cvt_pkrtz(a1.z * b1.z, a1.w * b1.w);
            va = ua.v; vb = ub.v; vaa = uaa.v; vbb = ubb.v; vab = uab.v;
        }
        const int o = r * XP + t8 * 8;          // 16B-aligned
        *(h8*)&smem[0 * XQS + o] = va;
        *(h8*)&smem[1 * XQS + o] = vb;
        *(h8*)&smem[2 * XQS + o] = vaa;
        *(h8*)&smem[3 * XQS + o] = vbb;
        *(h8*)&smem[4 * XQS + o] = vab;
    }
    __syncthreads();

    // ---- h-conv MFMA: wave w owns output-col N-tile w (cols 16w..16w+15) ----
    // Band p = c+3 .. c+13 => N-tile k-step sets: w0:{0} w1:{0,1} w2:{1} w3:{1,2}
    const int ksb  = (w >= 2) ? 1 : 0;
    const int nks  = (w & 1) ? 2 : 1;
    const int hoff = 16 * w + l15 + 3;
    const h8 bh0 = bfrag(ksb, grp8, hoff);
    h8 bh1 = {};
    if (nks == 2) bh1 = bfrag(ksb + 1, grp8, hoff);

    f32x4 acc[5][3] = {};                        // [quantity][M-tile of h-rows]
#pragma unroll
    for (int Mt = 0; Mt < 3; ++Mt) {
        const int arow = (16 * Mt + l15) * XP + grp8;
#pragma unroll
        for (int q = 0; q < 5; ++q) {
            const h8 af = *(const h8*)&smem[q * XQS + arow + ksb * 32];
            acc[q][Mt] = __builtin_amdgcn_mfma_f32_16x16x32_f16(af, bh0, acc[q][Mt], 0, 0, 0);
        }
        if (nks == 2) {
#pragma unroll
            for (int q = 0; q < 5; ++q) {
                const h8 af = *(const h8*)&smem[q * XQS + arow + ksb * 32 + 32];
                acc[q][Mt] = __builtin_amdgcn_mfma_f32_16x16x32_f16(af, bh1, acc[q][Mt], 0, 0, 0);
            }
        }
    }
    __syncthreads();                             // X fully consumed; reuse smem as Ht

    // ---- transpose-store D1 -> Ht[5][64][72] (f16), zero pad j=48..63 ----
#pragma unroll
    for (int q = 0; q < 5; ++q) {
#pragma unroll
        for (int Mt = 0; Mt < 3; ++Mt) {
            union { h2v h2[2]; h4 v; } u;
            u.h2[0] = __builtin_amdgcn_cvt_pkrtz(acc[q][Mt][0], acc[q][Mt][1]);
            u.h2[1] = __builtin_amdgcn_cvt_pkrtz(acc[q][Mt][2], acc[q][Mt][3]);
            // D1 lane holds col = 16w+l15, rows 16Mt+grp4..+3 -> contiguous along j
            *(h4*)&smem[q * HTQS + (16 * w + l15) * HTP + 16 * Mt + grp4] = u.v;
        }
    }
    {
        const h4 z4 = {};
        for (int i = tid; i < 5 * 256; i += 256) {   // Ht[q][c][48..63] = 0
            const int q = i >> 8, rem = i & 255, c = rem >> 2, jg = rem & 3;
            *(h4*)&smem[q * HTQS + c * HTP + 48 + (jg << 2)] = z4;
        }
    }
    __syncthreads();

    // ---- v-conv MFMA: wave w owns col M-tile w; N-tiles = out-row halves ----
    const h8 bv0 = bfrag(0, grp8, l15);          // N-tile 0 (rows 0..15),  k-step 0
    const h8 bv1 = bfrag(0, grp8, 16 + l15);     // N-tile 1 (rows 16..31), k-step 0
    const h8 bv2 = bfrag(1, grp8, 16 + l15);     // N-tile 1,               k-step 1
    f32x4 acc2[5][2] = {};
    const int abase = (16 * w + l15) * HTP + grp8;
#pragma unroll
    for (int q = 0; q < 5; ++q) {
        const h8 a0 = *(const h8*)&smem[q * HTQS + abase];
        const h8 a1 = *(const h8*)&smem[q * HTQS + abase + 32];
        acc2[q][0] = __builtin_amdgcn_mfma_f32_16x16x32_f16(a0, bv0, acc2[q][0], 0, 0, 0);
        acc2[q][1] = __builtin_amdgcn_mfma_f32_16x16x32_f16(a0, bv1, acc2[q][1], 0, 0, 0);
        acc2[q][1] = __builtin_amdgcn_mfma_f32_16x16x32_f16(a1, bv2, acc2[q][1], 0, 0, 0);
    }

    // ---- SSIM map on D2 fragments (4 px per frag per lane, 8 px/thread) ----
    float local = 0.f;
#pragma unroll
    for (int nt = 0; nt < 2; ++nt) {
        const f32x4 m1 = acc2[0][nt] * rs;
        const f32x4 m2 = acc2[1][nt] * rs;
        const f32x4 q1 = acc2[2][nt] * rs;
        const f32x4 q2 = acc2[3][nt] * rs;
        const f32x4 pp = acc2[4][nt] * rs;
        const f32x4 mu1s = m1 * m1, mu2s = m2 * m2, mu12 = m1 * m2;
        const f32x4 sg1 = q1 - mu1s, sg2 = q2 - mu2s, sg12 = pp - mu12;
        const f32x4 num = (2.f * mu12 + C1) * (2.f * sg12 + C2);
        const f32x4 den = (mu1s + mu2s + C1) * (sg1 + sg2 + C2) + 1e-12f;
#pragma unroll
        for (int e = 0; e < 4; ++e)
            local += num[e] * __builtin_amdgcn_rcpf(den[e]);
    }

    // ---- block reduction ----
#pragma unroll
    for (int off = 32; off > 0; off >>= 1)
        local += __shfl_down(local, off, 64);
    if ((tid & 63) == 0) wsums[tid >> 6] = local;
    __syncthreads();
    if (tid == 0) {
        const double bsum = (double)(wsums[0] + wsums[1] + wsums[2] + wsums[3]);
        if (mode == 0) {
            const int bid = (blockIdx.z * NBLKY + blockIdx.y) * NBLKX + blockIdx.x;
            sink[bid] = bsum;
        } else {
            atomicAdd(sink, bsum);
        }
    }
}

__global__ __launch_bounds__(256) void ssim_finalize(const double* __restrict__ partial,
                                                     float* __restrict__ out, int count) {
    __shared__ double ws[4];
    double s = 0.0;
    for (int i = threadIdx.x; i < count; i += 256) s += partial[i];
#pragma unroll
    for (int off = 32; off > 0; off >>= 1)
        s += __shfl_down(s, off, 64);
    const int lane = threadIdx.x & 63, wave = threadIdx.x >> 6;
    if (lane == 0) ws[wave] = s;
    __syncthreads();
    if (threadIdx.x == 0) {
        const double tot = ws[0] + ws[1] + ws[2] + ws[3];
        const double n = (double)NBC * IMG_H * IMG_W;
        out[0] = (float)(1.0 - tot / n);
    }
}

extern "C" void kernel_launch(void* const* d_in, const int* in_sizes, int n_in,
                              void* d_out, int out_size, void* d_ws, size_t ws_size,
                              hipStream_t stream) {
    const float* sr = (const float*)d_in[0];
    const float* hr = (const float*)d_in[1];
    float* out = (float*)d_out;
    const dim3 grid(NBLKX, NBLKY, NBC);

    if (ws_size >= (size_t)NBLK * sizeof(double)) {
        double* partial = (double*)d_ws; // fully overwritten each call
        ssim_main<<<grid, dim3(256), 0, stream>>>(sr, hr, partial, 0);
        ssim_finalize<<<dim3(1), dim3(256), 0, stream>>>(partial, out, NBLK);
    } else {
        double* acc = (double*)d_ws;
        ssim_init<<<dim3(1), dim3(64), 0, stream>>>(acc);
        ssim_main<<<grid, dim3(256), 0, stream>>>(sr, hr, acc, 1);
        ssim_finalize<<<dim3(1), dim3(256), 0, stream>>>(acc, out, 1);
    }
}

// Round 3
// 148.239 us; speedup vs baseline: 1.2203x; 1.0826x over previous
//
#include <hip/hip_runtime.h>

// SSIM loss, R8. R7 post-mortem: 93->68 us; VALUBusy 55%, MfmaUtil 8.3%,
// conflicts 5.2M (structural: all LDS strides ==0 mod 4 dw -> 8-bank subsets),
// weight-gen ~40 expf/thread ~12-15% of issue, staging latency exposed 2.4x.
// R8 (structure unchanged from R7: h-conv + v-conv on MFMA, f16 LDS planes):
//  - weights: hardcoded f32 constants -> 128-half LDS table; fragments = 8x
//    ds_read_u16 (imm offsets) instead of analytic expf build. rs compensation
//    computed exactly from stored f16 table values (broadcast reads).
//  - staging: 768-task space (r=i>>4, c8=i&15; no integer division), all 12
//    float4 loads hoisted before converts (single latency exposure), products
//    via v_pk_mul_f32 (f32x2).
//  - dropped Ht zero-fill (pad rows hit exactly-zero weights; stale aliased X
//    bytes are always finite f16) and the pre-v-conv barrier (wave w reads only
//    Ht cols [16w,16w+16) which wave w itself wrote; lgkmcnt orders it).

typedef __attribute__((ext_vector_type(2))) float  f32x2;
typedef __attribute__((ext_vector_type(4))) float  f32x4;
typedef __fp16 f16;
typedef __attribute__((ext_vector_type(2))) __fp16 h2v;
typedef __attribute__((ext_vector_type(4))) __fp16 h4;
typedef __attribute__((ext_vector_type(8))) __fp16 h8;

constexpr int IMG_H = 512;
constexpr int IMG_W = 512;
constexpr int NBC   = 48;                  // B*C planes
constexpr int TW    = 64;                  // output tile width
constexpr int TH    = 32;                  // output tile height
constexpr int NBLKX = IMG_W / TW;          // 8
constexpr int NBLKY = IMG_H / TH;          // 16
constexpr int NBLK  = NBLKX * NBLKY * NBC; // 6144

constexpr int XP   = 104;                  // X pitch (halves)
constexpr int XR   = 48;                   // X rows (42 data + 6 zero pad)
constexpr int XQS  = XR * XP;              // 4992 halves per quantity plane
constexpr int HTP  = 72;                   // Ht pitch (halves)
constexpr int HTQS = 64 * HTP;             // 4608 halves per quantity plane
constexpr int SMEMH = 5 * XQS;             // 24960 halves = 49920 B
static_assert(5 * HTQS <= SMEMH, "Ht must fit in X union");

constexpr float C1 = 1.0e-4f;
constexpr float C2 = 9.0e-4f;

// Normalized gaussian g[d] = exp(-(d-5)^2/4.5)/sum, f32-rounded.
__device__ const float GW[11] = {
    0.00102838f, 0.00759876f, 0.03600077f, 0.10936070f, 0.21300553f,
    0.26601172f, 0.21300553f, 0.10936070f, 0.03600077f, 0.00759876f,
    0.00102838f};

// Read an 8-half banded-weight fragment window from the LDS g-table.
__device__ __forceinline__ h8 ldfrag(const f16* __restrict__ gtab, int base) {
    h8 b;
#pragma unroll
    for (int i = 0; i < 8; ++i) b[i] = gtab[base + i];
    return b;
}

__global__ __launch_bounds__(64) void ssim_init(double* acc) {
    if (threadIdx.x == 0) acc[0] = 0.0;
}

__global__ __launch_bounds__(256, 3) void ssim_main(const float* __restrict__ sr,
                                                    const float* __restrict__ hr,
                                                    double* __restrict__ sink,
                                                    int mode) {
    __shared__ __align__(16) f16 smem[SMEMH];   // X[5][48][104] / Ht[5][64][72] alias
    __shared__ __align__(8)  f16 gtab[128];     // zero-padded weights, g at [66..76]
    __shared__ float wsums[4];

    const int tid  = threadIdx.x;
    const int w    = tid >> 6;                  // wave id
    const int lane = tid & 63;
    const int l15  = lane & 15;
    const int grp8 = (lane >> 4) << 3;
    const int grp4 = (lane >> 4) << 2;

    const int bc  = blockIdx.z;
    const int gr0 = blockIdx.y * TH - 5;        // global row of X row 0
    const int gc0 = blockIdx.x * TW - 8;        // global col of X col 0 (f4-aligned)
    const float* __restrict__ srp = sr + (size_t)bc * IMG_H * IMG_W;
    const float* __restrict__ hrp = hr + (size_t)bc * IMG_H * IMG_W;

    // ---- staging: issue ALL loads first (3 tasks x 2 float4 x 2 images) ----
    const int c8  = tid & 15;                   // col-chunk (valid < 13)
    const int r0s = tid >> 4;                   // row for task 0; +16 per task
    float4 La0[3], La1[3], Lb0[3], Lb1[3];
#pragma unroll
    for (int t = 0; t < 3; ++t) {
        const int r  = r0s + 16 * t;
        const int gr = gr0 + r;
        const int gc = gc0 + c8 * 8;
        La0[t] = La1[t] = Lb0[t] = Lb1[t] = (float4){0.f, 0.f, 0.f, 0.f};
        if ((c8 < 13) & (r < 42) &
            ((unsigned)gr < (unsigned)IMG_H) & ((unsigned)gc < (unsigned)IMG_W)) {
            const float4* pa = (const float4*)&srp[(size_t)gr * IMG_W + gc];
            const float4* pb = (const float4*)&hrp[(size_t)gr * IMG_W + gc];
            La0[t] = pa[0]; La1[t] = pa[1];
            Lb0[t] = pb[0]; Lb1[t] = pb[1];
        }
    }

    // ---- g-table fill (overlaps load latency) ----
    if (tid < 128) {
        const int d = tid - 66;
        float v = 0.f;
        if ((unsigned)d <= 10u) v = GW[d];
        gtab[tid] = (f16)v;
    }

    // ---- convert + store X planes (pk-mul products, pkrtz packing) ----
    if (c8 < 13) {
#pragma unroll
        for (int t = 0; t < 3; ++t) {
            const int r = r0s + 16 * t;         // always < 48
            const f32x2* a0 = (const f32x2*)&La0[t];
            const f32x2* a1 = (const f32x2*)&La1[t];
            const f32x2* b0 = (const f32x2*)&Lb0[t];
            const f32x2* b1 = (const f32x2*)&Lb1[t];
            const f32x2 aa0 = a0[0] * a0[0], aa1 = a0[1] * a0[1];
            const f32x2 aa2 = a1[0] * a1[0], aa3 = a1[1] * a1[1];
            const f32x2 bb0 = b0[0] * b0[0], bb1 = b0[1] * b0[1];
            const f32x2 bb2 = b1[0] * b1[0], bb3 = b1[1] * b1[1];
            const f32x2 ab0 = a0[0] * b0[0], ab1 = a0[1] * b0[1];
            const f32x2 ab2 = a1[0] * b1[0], ab3 = a1[1] * b1[1];
            union { h2v h2[4]; h8 v; } uva, uvb, uaa, ubb, uab;
            uva.h2[0] = __builtin_amdgcn_cvt_pkrtz(a0[0].x, a0[0].y);
            uva.h2[1] = __builtin_amdgcn_cvt_pkrtz(a0[1].x, a0[1].y);
            uva.h2[2] = __builtin_amdgcn_cvt_pkrtz(a1[0].x, a1[0].y);
            uva.h2[3] = __builtin_amdgcn_cvt_pkrtz(a1[1].x, a1[1].y);
            uvb.h2[0] = __builtin_amdgcn_cvt_pkrtz(b0[0].x, b0[0].y);
            uvb.h2[1] = __builtin_amdgcn_cvt_pkrtz(b0[1].x, b0[1].y);
            uvb.h2[2] = __builtin_amdgcn_cvt_pkrtz(b1[0].x, b1[0].y);
            uvb.h2[3] = __builtin_amdgcn_cvt_pkrtz(b1[1].x, b1[1].y);
            uaa.h2[0] = __builtin_amdgcn_cvt_pkrtz(aa0.x, aa0.y);
            uaa.h2[1] = __builtin_amdgcn_cvt_pkrtz(aa1.x, aa1.y);
            uaa.h2[2] = __builtin_amdgcn_cvt_pkrtz(aa2.x, aa2.y);
            uaa.h2[3] = __builtin_amdgcn_cvt_pkrtz(aa3.x, aa3.y);
            ubb.h2[0] = __builtin_amdgcn_cvt_pkrtz(bb0.x, bb0.y);
            ubb.h2[1] = __builtin_amdgcn_cvt_pkrtz(bb1.x, bb1.y);
            ubb.h2[2] = __builtin_amdgcn_cvt_pkrtz(bb2.x, bb2.y);
            ubb.h2[3] = __builtin_amdgcn_cvt_pkrtz(bb3.x, bb3.y);
            uab.h2[0] = __builtin_amdgcn_cvt_pkrtz(ab0.x, ab0.y);
            uab.h2[1] = __builtin_amdgcn_cvt_pkrtz(ab1.x, ab1.y);
            uab.h2[2] = __builtin_amdgcn_cvt_pkrtz(ab2.x, ab2.y);
            uab.h2[3] = __builtin_amdgcn_cvt_pkrtz(ab3.x, ab3.y);
            const int o = r * XP + c8 * 8;      // 16B-aligned
            *(h8*)&smem[0 * XQS + o] = uva.v;
            *(h8*)&smem[1 * XQS + o] = uvb.v;
            *(h8*)&smem[2 * XQS + o] = uaa.v;
            *(h8*)&smem[3 * XQS + o] = ubb.v;
            *(h8*)&smem[4 * XQS + o] = uab.v;
        }
    }
    __syncthreads();

    // ---- exact f16-rounding compensation from the stored table ----
    float s16 = 0.f;
#pragma unroll
    for (int d = 0; d <= 10; ++d) s16 += (float)gtab[66 + d];
    const float rs = 1.0f / (s16 * s16);

    // ---- h-conv MFMA: wave w owns output-col N-tile w (cols 16w..16w+15) ----
    // Band j = c+3 .. c+13 => k-step sets: w0:{0} w1:{0,1} w2:{1} w3:{1,2}
    const int ksb = (w >= 2) ? 1 : 0;
    const int nks = (w & 1) ? 2 : 1;
    const int bhb = 66 + ksb * 32 + grp8 - (16 * w + l15 + 3);
    const h8 bh0 = ldfrag(gtab, bhb);
    h8 bh1 = {};
    if (nks == 2) bh1 = ldfrag(gtab, bhb + 32);

    f32x4 acc[5][3] = {};                        // [quantity][M-tile of h-rows]
#pragma unroll
    for (int Mt = 0; Mt < 3; ++Mt) {
        const int arow = (16 * Mt + l15) * XP + grp8;
#pragma unroll
        for (int q = 0; q < 5; ++q) {
            const h8 af = *(const h8*)&smem[q * XQS + arow + ksb * 32];
            acc[q][Mt] = __builtin_amdgcn_mfma_f32_16x16x32_f16(af, bh0, acc[q][Mt], 0, 0, 0);
        }
        if (nks == 2) {
#pragma unroll
            for (int q = 0; q < 5; ++q) {
                const h8 af = *(const h8*)&smem[q * XQS + arow + ksb * 32 + 32];
                acc[q][Mt] = __builtin_amdgcn_mfma_f32_16x16x32_f16(af, bh1, acc[q][Mt], 0, 0, 0);
            }
        }
    }
    __syncthreads();                             // X fully consumed; reuse as Ht

    // ---- transpose-store D1 -> Ht[5][64][72] f16 ----
    // No zero-fill of j>=48: those taps have exactly-zero weights and the
    // stale aliased X bytes are always finite f16. No barrier before v-conv:
    // wave w reads only Ht cols [16w,16w+16) which wave w itself wrote.
#pragma unroll
    for (int q = 0; q < 5; ++q) {
#pragma unroll
        for (int Mt = 0; Mt < 3; ++Mt) {
            union { h2v h2[2]; h4 v; } u;
            u.h2[0] = __builtin_amdgcn_cvt_pkrtz(acc[q][Mt][0], acc[q][Mt][1]);
            u.h2[1] = __builtin_amdgcn_cvt_pkrtz(acc[q][Mt][2], acc[q][Mt][3]);
            *(h4*)&smem[q * HTQS + (16 * w + l15) * HTP + 16 * Mt + grp4] = u.v;
        }
    }

    // ---- v-conv MFMA: wave w owns col M-tile w; N-tiles = out-row halves ----
    const h8 bv0 = ldfrag(gtab, 66 + grp8 - l15);
    const h8 bv1 = ldfrag(gtab, 66 + grp8 - 16 - l15);
    const h8 bv2 = ldfrag(gtab, 66 + 32 + grp8 - 16 - l15);
    f32x4 acc2[5][2] = {};
    const int abase = (16 * w + l15) * HTP + grp8;
#pragma unroll
    for (int q = 0; q < 5; ++q) {
        const h8 a0 = *(const h8*)&smem[q * HTQS + abase];
        const h8 a1 = *(const h8*)&smem[q * HTQS + abase + 32];
        acc2[q][0] = __builtin_amdgcn_mfma_f32_16x16x32_f16(a0, bv0, acc2[q][0], 0, 0, 0);
        acc2[q][1] = __builtin_amdgcn_mfma_f32_16x16x32_f16(a0, bv1, acc2[q][1], 0, 0, 0);
        acc2[q][1] = __builtin_amdgcn_mfma_f32_16x16x32_f16(a1, bv2, acc2[q][1], 0, 0, 0);
    }

    // ---- SSIM map on D2 fragments (8 px/thread) ----
    float local = 0.f;
#pragma unroll
    for (int nt = 0; nt < 2; ++nt) {
        const f32x4 m1 = acc2[0][nt] * rs;
        const f32x4 m2 = acc2[1][nt] * rs;
        const f32x4 q1 = acc2[2][nt] * rs;
        const f32x4 q2 = acc2[3][nt] * rs;
        const f32x4 pp = acc2[4][nt] * rs;
        const f32x4 mu1s = m1 * m1, mu2s = m2 * m2, mu12 = m1 * m2;
        const f32x4 sg1 = q1 - mu1s, sg2 = q2 - mu2s, sg12 = pp - mu12;
        const f32x4 num = (2.f * mu12 + C1) * (2.f * sg12 + C2);
        const f32x4 den = (mu1s + mu2s + C1) * (sg1 + sg2 + C2) + 1e-12f;
#pragma unroll
        for (int e = 0; e < 4; ++e)
            local += num[e] * __builtin_amdgcn_rcpf(den[e]);
    }

    // ---- block reduction ----
#pragma unroll
    for (int off = 32; off > 0; off >>= 1)
        local += __shfl_down(local, off, 64);
    if ((tid & 63) == 0) wsums[tid >> 6] = local;
    __syncthreads();
    if (tid == 0) {
        const double bsum = (double)(wsums[0] + wsums[1] + wsums[2] + wsums[3]);
        if (mode == 0) {
            const int bid = (blockIdx.z * NBLKY + blockIdx.y) * NBLKX + blockIdx.x;
            sink[bid] = bsum;
        } else {
            atomicAdd(sink, bsum);
        }
    }
}

__global__ __launch_bounds__(256) void ssim_finalize(const double* __restrict__ partial,
                                                     float* __restrict__ out, int count) {
    __shared__ double ws[4];
    double s = 0.0;
    for (int i = threadIdx.x; i < count; i += 256) s += partial[i];
#pragma unroll
    for (int off = 32; off > 0; off >>= 1)
        s += __shfl_down(s, off, 64);
    const int lane = threadIdx.x & 63, wave = threadIdx.x >> 6;
    if (lane == 0) ws[wave] = s;
    __syncthreads();
    if (threadIdx.x == 0) {
        const double tot = ws[0] + ws[1] + ws[2] + ws[3];
        const double n = (double)NBC * IMG_H * IMG_W;
        out[0] = (float)(1.0 - tot / n);
    }
}

extern "C" void kernel_launch(void* const* d_in, const int* in_sizes, int n_in,
                              void* d_out, int out_size, void* d_ws, size_t ws_size,
                              hipStream_t stream) {
    const float* sr = (const float*)d_in[0];
    const float* hr = (const float*)d_in[1];
    float* out = (float*)d_out;
    const dim3 grid(NBLKX, NBLKY, NBC);

    if (ws_size >= (size_t)NBLK * sizeof(double)) {
        double* partial = (double*)d_ws; // fully overwritten each call
        ssim_main<<<grid, dim3(256), 0, stream>>>(sr, hr, partial, 0);
        ssim_finalize<<<dim3(1), dim3(256), 0, stream>>>(partial, out, NBLK);
    } else {
        double* acc = (double*)d_ws;
        ssim_init<<<dim3(1), dim3(64), 0, stream>>>(acc);
        ssim_main<<<grid, dim3(256), 0, stream>>>(sr, hr, acc, 1);
        ssim_finalize<<<dim3(1), dim3(256), 0, stream>>>(acc, out, 1);
    }
}

// Round 4
// 133.857 us; speedup vs baseline: 1.3514x; 1.1074x over previous
//
#include <hip/hip_runtime.h>

// SSIM loss, R9. R8 post-mortem: 56.4 us; VALUBusy 31%, MfmaUtil 10%, HBM 21%
// -> latency-bound, only 3 blocks/CU (LDS 50.7KB). R9:
//  - 4 planes not 5: SSIM needs only sigma1^2+sigma2^2 (a sum), so convolve
//    s = a^2+b^2 as ONE plane. LDS 4*48*104*2 = 39,936B -> 4 blocks/CU.
//  - per-wave A k-offset (16w) in h-conv: band fits one 32-wide k-step ->
//    12 MFMA (was ~22.5), B fragment wave-independent g[kl-l15-3].
//  - per-N-tile A k-offset (16nt) in v-conv: ONE shared B fragment g[kl-l15],
//    8 MFMA (was 15), zero stale-byte reads.
//  - max A col read 80 (was 96): staging 10 col-chunks not 13 (-23% loads).
// Retained from R8: LDS g-table weights (no expf), hoisted staging loads,
// pk-mul products, no Ht zero-fill, no pre-v-conv barrier, rs compensation
// computed exactly from the stored f16 table.

typedef __attribute__((ext_vector_type(2))) float  f32x2;
typedef __attribute__((ext_vector_type(4))) float  f32x4;
typedef __fp16 f16;
typedef __attribute__((ext_vector_type(2))) __fp16 h2v;
typedef __attribute__((ext_vector_type(4))) __fp16 h4;
typedef __attribute__((ext_vector_type(8))) __fp16 h8;

constexpr int IMG_H = 512;
constexpr int IMG_W = 512;
constexpr int NBC   = 48;                  // B*C planes
constexpr int TW    = 64;                  // output tile width
constexpr int TH    = 32;                  // output tile height
constexpr int NBLKX = IMG_W / TW;          // 8
constexpr int NBLKY = IMG_H / TH;          // 16
constexpr int NBLK  = NBLKX * NBLKY * NBC; // 6144

constexpr int XP   = 104;                  // X pitch (halves): 52 dw, 8-period stagger
constexpr int XR   = 48;                   // X rows (42 data + 6 zero pad)
constexpr int XQS  = XR * XP;              // 4992 halves per plane
constexpr int HTP  = 72;                   // Ht pitch (halves)
constexpr int HTQS = 64 * HTP;             // 4608 halves per plane
constexpr int SMEMH = 4 * XQS;             // 19968 halves = 39,936 B
static_assert(4 * HTQS <= SMEMH, "Ht must fit in X union");

constexpr float C1 = 1.0e-4f;
constexpr float C2 = 9.0e-4f;

// Normalized gaussian g[d] = exp(-(d-5)^2/4.5)/sum, f32-rounded.
__device__ const float GW[11] = {
    0.00102838f, 0.00759876f, 0.03600077f, 0.10936070f, 0.21300553f,
    0.26601172f, 0.21300553f, 0.10936070f, 0.03600077f, 0.00759876f,
    0.00102838f};

__device__ __forceinline__ h8 ldfrag(const f16* __restrict__ gtab, int base) {
    h8 b;
#pragma unroll
    for (int i = 0; i < 8; ++i) b[i] = gtab[base + i];
    return b;
}

__global__ __launch_bounds__(64) void ssim_init(double* acc) {
    if (threadIdx.x == 0) acc[0] = 0.0;
}

__global__ __launch_bounds__(256, 4) void ssim_main(const float* __restrict__ sr,
                                                    const float* __restrict__ hr,
                                                    double* __restrict__ sink,
                                                    int mode) {
    __shared__ __align__(16) f16 smem[SMEMH];   // X[4][48][104] / Ht[4][64][72] alias
    __shared__ __align__(8)  f16 gtab[128];     // zero-padded weights, g at [66..76]
    __shared__ float wsums[4];

    const int tid  = threadIdx.x;
    const int w    = tid >> 6;                  // wave id
    const int lane = tid & 63;
    const int l15  = lane & 15;
    const int grp8 = (lane >> 4) << 3;
    const int grp4 = (lane >> 4) << 2;

    const int bc  = blockIdx.z;
    const int gr0 = blockIdx.y * TH - 5;        // global row of X row 0
    const int gc0 = blockIdx.x * TW - 8;        // global col of X col 0 (f4-aligned)
    const float* __restrict__ srp = sr + (size_t)bc * IMG_H * IMG_W;
    const float* __restrict__ hrp = hr + (size_t)bc * IMG_H * IMG_W;

    // ---- staging: issue ALL loads first (3 tasks x 2 float4 x 2 images) ----
    // Only col-chunks c8<10 (X cols 0..79) are ever read by h-conv.
    const int c8  = tid & 15;
    const int r0s = tid >> 4;
    float4 La0[3], La1[3], Lb0[3], Lb1[3];
#pragma unroll
    for (int t = 0; t < 3; ++t) {
        const int r  = r0s + 16 * t;
        const int gr = gr0 + r;
        const int gc = gc0 + c8 * 8;
        La0[t] = La1[t] = Lb0[t] = Lb1[t] = (float4){0.f, 0.f, 0.f, 0.f};
        if ((c8 < 10) & (r < 42) &
            ((unsigned)gr < (unsigned)IMG_H) & ((unsigned)gc < (unsigned)IMG_W)) {
            const float4* pa = (const float4*)&srp[(size_t)gr * IMG_W + gc];
            const float4* pb = (const float4*)&hrp[(size_t)gr * IMG_W + gc];
            La0[t] = pa[0]; La1[t] = pa[1];
            Lb0[t] = pb[0]; Lb1[t] = pb[1];
        }
    }

    // ---- g-table fill (overlaps load latency) ----
    if (tid < 128) {
        const int d = tid - 66;
        float v = 0.f;
        if ((unsigned)d <= 10u) v = GW[d];
        gtab[tid] = (f16)v;
    }

    // ---- convert + store X planes: a, b, a^2+b^2, a*b ----
    if (c8 < 10) {
#pragma unroll
        for (int t = 0; t < 3; ++t) {
            const int r = r0s + 16 * t;         // < 48
            const f32x2* a0 = (const f32x2*)&La0[t];
            const f32x2* a1 = (const f32x2*)&La1[t];
            const f32x2* b0 = (const f32x2*)&Lb0[t];
            const f32x2* b1 = (const f32x2*)&Lb1[t];
            const f32x2 s0 = a0[0] * a0[0] + b0[0] * b0[0];
            const f32x2 s1 = a0[1] * a0[1] + b0[1] * b0[1];
            const f32x2 s2 = a1[0] * a1[0] + b1[0] * b1[0];
            const f32x2 s3 = a1[1] * a1[1] + b1[1] * b1[1];
            const f32x2 p0 = a0[0] * b0[0], p1 = a0[1] * b0[1];
            const f32x2 p2 = a1[0] * b1[0], p3 = a1[1] * b1[1];
            union { h2v h2[4]; h8 v; } uva, uvb, uss, uab;
            uva.h2[0] = __builtin_amdgcn_cvt_pkrtz(a0[0].x, a0[0].y);
            uva.h2[1] = __builtin_amdgcn_cvt_pkrtz(a0[1].x, a0[1].y);
            uva.h2[2] = __builtin_amdgcn_cvt_pkrtz(a1[0].x, a1[0].y);
            uva.h2[3] = __builtin_amdgcn_cvt_pkrtz(a1[1].x, a1[1].y);
            uvb.h2[0] = __builtin_amdgcn_cvt_pkrtz(b0[0].x, b0[0].y);
            uvb.h2[1] = __builtin_amdgcn_cvt_pkrtz(b0[1].x, b0[1].y);
            uvb.h2[2] = __builtin_amdgcn_cvt_pkrtz(b1[0].x, b1[0].y);
            uvb.h2[3] = __builtin_amdgcn_cvt_pkrtz(b1[1].x, b1[1].y);
            uss.h2[0] = __builtin_amdgcn_cvt_pkrtz(s0.x, s0.y);
            uss.h2[1] = __builtin_amdgcn_cvt_pkrtz(s1.x, s1.y);
            uss.h2[2] = __builtin_amdgcn_cvt_pkrtz(s2.x, s2.y);
            uss.h2[3] = __builtin_amdgcn_cvt_pkrtz(s3.x, s3.y);
            uab.h2[0] = __builtin_amdgcn_cvt_pkrtz(p0.x, p0.y);
            uab.h2[1] = __builtin_amdgcn_cvt_pkrtz(p1.x, p1.y);
            uab.h2[2] = __builtin_amdgcn_cvt_pkrtz(p2.x, p2.y);
            uab.h2[3] = __builtin_amdgcn_cvt_pkrtz(p3.x, p3.y);
            const int o = r * XP + c8 * 8;      // 16B-aligned
            *(h8*)&smem[0 * XQS + o] = uva.v;
            *(h8*)&smem[1 * XQS + o] = uvb.v;
            *(h8*)&smem[2 * XQS + o] = uss.v;
            *(h8*)&smem[3 * XQS + o] = uab.v;
        }
    }
    __syncthreads();

    // ---- exact f16-rounding compensation from the stored table ----
    float s16 = 0.f;
#pragma unroll
    for (int d = 0; d <= 10; ++d) s16 += (float)gtab[66 + d];
    const float rs = 1.0f / (s16 * s16);

    // ---- h-conv MFMA: wave w owns out-col tile w; A at k-offset 16w ----
    // B[kl][n=l15] = g[kl - l15 - 3], wave-independent; one k-step.
    const h8 bh = ldfrag(gtab, 63 + grp8 - l15);
    f32x4 acc[4][3] = {};                        // [plane][M-tile of h-rows]
#pragma unroll
    for (int Mt = 0; Mt < 3; ++Mt) {
        const int arow = (16 * Mt + l15) * XP + 16 * w + grp8;
#pragma unroll
        for (int q = 0; q < 4; ++q) {
            const h8 af = *(const h8*)&smem[q * XQS + arow];
            acc[q][Mt] = __builtin_amdgcn_mfma_f32_16x16x32_f16(af, bh, acc[q][Mt], 0, 0, 0);
        }
    }
    __syncthreads();                             // X consumed; reuse as Ht

    // ---- transpose-store D1 -> Ht[4][64][72] f16 ----
    // No barrier after: wave w reads only Ht cols [16w,16w+16) it wrote itself.
#pragma unroll
    for (int q = 0; q < 4; ++q) {
#pragma unroll
        for (int Mt = 0; Mt < 3; ++Mt) {
            union { h2v h2[2]; h4 v; } u;
            u.h2[0] = __builtin_amdgcn_cvt_pkrtz(acc[q][Mt][0], acc[q][Mt][1]);
            u.h2[1] = __builtin_amdgcn_cvt_pkrtz(acc[q][Mt][2], acc[q][Mt][3]);
            *(h4*)&smem[q * HTQS + (16 * w + l15) * HTP + 16 * Mt + grp4] = u.v;
        }
    }

    // ---- v-conv MFMA: wave w owns col tile w; A k-offset 16*nt per N-tile ----
    // B[kl][n=l15] = g[kl - l15], shared by both N-tiles.
    const h8 bv = ldfrag(gtab, 66 + grp8 - l15);
    f32x4 acc2[4][2] = {};
    const int abase = (16 * w + l15) * HTP + grp8;
#pragma unroll
    for (int q = 0; q < 4; ++q) {
        const h8 a0 = *(const h8*)&smem[q * HTQS + abase];       // rows 0-15
        const h8 a1 = *(const h8*)&smem[q * HTQS + abase + 16];  // rows 16-31
        acc2[q][0] = __builtin_amdgcn_mfma_f32_16x16x32_f16(a0, bv, acc2[q][0], 0, 0, 0);
        acc2[q][1] = __builtin_amdgcn_mfma_f32_16x16x32_f16(a1, bv, acc2[q][1], 0, 0, 0);
    }

    // ---- SSIM map on D2 fragments (8 px/thread) ----
    float local = 0.f;
#pragma unroll
    for (int nt = 0; nt < 2; ++nt) {
        const f32x4 m1 = acc2[0][nt] * rs;
        const f32x4 m2 = acc2[1][nt] * rs;
        const f32x4 S  = acc2[2][nt] * rs;       // E[a^2+b^2]
        const f32x4 pp = acc2[3][nt] * rs;       // E[ab]
        const f32x4 mu1s = m1 * m1, mu2s = m2 * m2, mu12 = m1 * m2;
        const f32x4 sg12 = pp - mu12;
        const f32x4 sgs  = S - mu1s - mu2s;      // sigma1^2 + sigma2^2
        const f32x4 num = (2.f * mu12 + C1) * (2.f * sg12 + C2);
        const f32x4 den = (mu1s + mu2s + C1) * (sgs + C2) + 1e-12f;
#pragma unroll
        for (int e = 0; e < 4; ++e)
            local += num[e] * __builtin_amdgcn_rcpf(den[e]);
    }

    // ---- block reduction ----
#pragma unroll
    for (int off = 32; off > 0; off >>= 1)
        local += __shfl_down(local, off, 64);
    if ((tid & 63) == 0) wsums[tid >> 6] = local;
    __syncthreads();
    if (tid == 0) {
        const double bsum = (double)(wsums[0] + wsums[1] + wsums[2] + wsums[3]);
        if (mode == 0) {
            const int bid = (blockIdx.z * NBLKY + blockIdx.y) * NBLKX + blockIdx.x;
            sink[bid] = bsum;
        } else {
            atomicAdd(sink, bsum);
        }
    }
}

__global__ __launch_bounds__(256) void ssim_finalize(const double* __restrict__ partial,
                                                     float* __restrict__ out, int count) {
    __shared__ double ws[4];
    double s = 0.0;
    for (int i = threadIdx.x; i < count; i += 256) s += partial[i];
#pragma unroll
    for (int off = 32; off > 0; off >>= 1)
        s += __shfl_down(s, off, 64);
    const int lane = threadIdx.x & 63, wave = threadIdx.x >> 6;
    if (lane == 0) ws[wave] = s;
    __syncthreads();
    if (threadIdx.x == 0) {
        const double tot = ws[0] + ws[1] + ws[2] + ws[3];
        const double n = (double)NBC * IMG_H * IMG_W;
        out[0] = (float)(1.0 - tot / n);
    }
}

extern "C" void kernel_launch(void* const* d_in, const int* in_sizes, int n_in,
                              void* d_out, int out_size, void* d_ws, size_t ws_size,
                              hipStream_t stream) {
    const float* sr = (const float*)d_in[0];
    const float* hr = (const float*)d_in[1];
    float* out = (float*)d_out;
    const dim3 grid(NBLKX, NBLKY, NBC);

    if (ws_size >= (size_t)NBLK * sizeof(double)) {
        double* partial = (double*)d_ws; // fully overwritten each call
        ssim_main<<<grid, dim3(256), 0, stream>>>(sr, hr, partial, 0);
        ssim_finalize<<<dim3(1), dim3(256), 0, stream>>>(partial, out, NBLK);
    } else {
        double* acc = (double*)d_ws;
        ssim_init<<<dim3(1), dim3(64), 0, stream>>>(acc);
        ssim_main<<<grid, dim3(256), 0, stream>>>(sr, hr, acc, 1);
        ssim_finalize<<<dim3(1), dim3(256), 0, stream>>>(acc, out, 1);
    }
}

// Round 6
// 130.011 us; speedup vs baseline: 1.3914x; 1.0296x over previous
//
#include <hip/hip_runtime.h>

// SSIM loss, R10b: resubmission of R10 (bench was an infra failure —
// "MI355X container failed twice", no pytest/counters; same signature as R1
// which passed unchanged on resubmit). Kernel audited: full tile coverage,
// no hang path, uniform barriers, guarded loads, in-bounds LDS, same-wave
// LDS RAW ordering only (R9-proven pattern).
//
// R10 design (R9 post-mortem: 41.5 us; VALUBusy 37%, MfmaUtil 7%, HBM 28%,
// occupancy 33% -> ~50% stall: 6144 short blocks each pay cold ~900cy HBM
// latency + per-tile setup with nothing in flight behind it):
// persistent blocks. grid=1024 (4/CU), each block does 6 tiles at stride
// 1024 -> same (x,y) tile, BC plane += 8/iter. All addressing/guards/g-table/
// B-frags/rs are loop-invariant (computed once). Per iter: store X -> barrier
// -> ISSUE NEXT TILE'S LOADS (overlap h-conv; drained at barrier2) -> h-conv
// -> barrier -> transpose+v-conv+SSIM -> barrier. Reduction amortized 6x.
// y-neighbor blocks (dbid=8) round-robin to the same XCD -> halo L2 reuse.
// Retained: 4 planes (a,b,a2+b2,ab), one-k-step band trick, LDS g-table,
// f16 planes XP=104, rs compensation, no Ht zero-fill.

typedef __attribute__((ext_vector_type(2))) float  f32x2;
typedef __attribute__((ext_vector_type(4))) float  f32x4;
typedef __fp16 f16;
typedef __attribute__((ext_vector_type(2))) __fp16 h2v;
typedef __attribute__((ext_vector_type(4))) __fp16 h4;
typedef __attribute__((ext_vector_type(8))) __fp16 h8;

constexpr int IMG_H = 512;
constexpr int IMG_W = 512;
constexpr int PL    = IMG_H * IMG_W;       // plane stride (floats)
constexpr int NBC   = 48;                  // B*C planes
constexpr int TW    = 64;                  // output tile width
constexpr int TH    = 32;                  // output tile height
constexpr int NBLKX = IMG_W / TW;          // 8
constexpr int NBLKY = IMG_H / TH;          // 16
constexpr int NPERS = 1024;                // persistent blocks (4/CU)
constexpr int ITERS = NBLKX * NBLKY * NBC / NPERS; // 6

constexpr int XP   = 104;                  // X pitch (halves)
constexpr int XR   = 48;                   // X rows (42 data + 6 zero pad)
constexpr int XQS  = XR * XP;              // 4992 halves per plane
constexpr int HTP  = 72;                   // Ht pitch (halves)
constexpr int HTQS = 64 * HTP;             // 4608 halves per plane
constexpr int SMEMH = 4 * XQS;             // 19968 halves = 39,936 B
static_assert(4 * HTQS <= SMEMH, "Ht must fit in X union");

constexpr float C1 = 1.0e-4f;
constexpr float C2 = 9.0e-4f;

// Normalized gaussian g[d] = exp(-(d-5)^2/4.5)/sum, f32-rounded.
__device__ const float GW[11] = {
    0.00102838f, 0.00759876f, 0.03600077f, 0.10936070f, 0.21300553f,
    0.26601172f, 0.21300553f, 0.10936070f, 0.03600077f, 0.00759876f,
    0.00102838f};

__device__ __forceinline__ h8 ldfrag(const f16* __restrict__ gtab, int base) {
    h8 b;
#pragma unroll
    for (int i = 0; i < 8; ++i) b[i] = gtab[base + i];
    return b;
}

__global__ __launch_bounds__(64) void ssim_init(double* acc) {
    if (threadIdx.x == 0) acc[0] = 0.0;
}

__global__ __launch_bounds__(256, 4) void ssim_main(const float* __restrict__ sr,
                                                    const float* __restrict__ hr,
                                                    double* __restrict__ sink,
                                                    int mode) {
    __shared__ __align__(16) f16 smem[SMEMH];   // X[4][48][104] / Ht[4][64][72] alias
    __shared__ __align__(8)  f16 gtab[128];     // zero-padded weights, g at [66..76]
    __shared__ float wsums[4];

    const int tid  = threadIdx.x;
    const int w    = tid >> 6;                  // wave id
    const int lane = tid & 63;
    const int l15  = lane & 15;
    const int grp8 = (lane >> 4) << 3;
    const int grp4 = (lane >> 4) << 2;

    // tile (x,y) fixed for this block; BC plane steps by 8 per iteration
    const int bx  = blockIdx.x & 7;
    const int by  = (blockIdx.x >> 3) & 15;
    const int bc0 = blockIdx.x >> 7;            // 0..7
    const int gr0 = by * TH - 5;
    const int gc0 = bx * TW - 8;

    const float* __restrict__ srp = sr + (size_t)bc0 * PL;
    const float* __restrict__ hrp = hr + (size_t)bc0 * PL;
    const size_t PSTEP = (size_t)8 * PL;

    // ---- loop-invariant staging geometry ----
    const int c8  = tid & 15;
    const int r0s = tid >> 4;
    unsigned okm = 0;
    int off[3];
#pragma unroll
    for (int t = 0; t < 3; ++t) {
        const int r  = r0s + 16 * t;
        const int gr = gr0 + r;
        const int gc = gc0 + c8 * 8;
        if ((c8 < 10) & (r < 42) &
            ((unsigned)gr < (unsigned)IMG_H) & ((unsigned)gc < (unsigned)IMG_W))
            okm |= (1u << t);
        off[t] = gr * IMG_W + gc;
    }

    // ---- g-table fill ----
    if (tid < 128) {
        const int d = tid - 66;
        float v = 0.f;
        if ((unsigned)d <= 10u) v = GW[d];
        gtab[tid] = (f16)v;
    }

    // ---- rs compensation: pure-constant f16 round-trip (no LDS dependency) ----
    float s16 = 0.f;
#pragma unroll
    for (int d = 0; d <= 10; ++d) s16 += (float)(f16)GW[d];
    const float rs = 1.0f / (s16 * s16);

    // ---- prologue: load tile 0 ----
    float4 La0[3], La1[3], Lb0[3], Lb1[3];
#pragma unroll
    for (int t = 0; t < 3; ++t) {
        La0[t] = La1[t] = Lb0[t] = Lb1[t] = (float4){0.f, 0.f, 0.f, 0.f};
        if (okm & (1u << t)) {
            const float4* pa = (const float4*)&srp[off[t]];
            const float4* pb = (const float4*)&hrp[off[t]];
            La0[t] = pa[0]; La1[t] = pa[1];
            Lb0[t] = pb[0]; Lb1[t] = pb[1];
        }
    }
    __syncthreads();                            // gtab ready

    // ---- loop-invariant B fragments ----
    const h8 bh = ldfrag(gtab, 63 + grp8 - l15);   // h-conv: g[kl-l15-3]
    const h8 bv = ldfrag(gtab, 66 + grp8 - l15);   // v-conv: g[kl-l15]

    float local = 0.f;

    for (int iter = 0; iter < ITERS; ++iter) {
        // ---- convert + store X planes: a, b, a^2+b^2, a*b ----
        if (c8 < 10) {
#pragma unroll
            for (int t = 0; t < 3; ++t) {
                const int r = r0s + 16 * t;     // < 48
                const f32x2* a0 = (const f32x2*)&La0[t];
                const f32x2* a1 = (const f32x2*)&La1[t];
                const f32x2* b0 = (const f32x2*)&Lb0[t];
                const f32x2* b1 = (const f32x2*)&Lb1[t];
                const f32x2 s0 = a0[0] * a0[0] + b0[0] * b0[0];
                const f32x2 s1 = a0[1] * a0[1] + b0[1] * b0[1];
                const f32x2 s2 = a1[0] * a1[0] + b1[0] * b1[0];
                const f32x2 s3 = a1[1] * a1[1] + b1[1] * b1[1];
                const f32x2 p0 = a0[0] * b0[0], p1 = a0[1] * b0[1];
                const f32x2 p2 = a1[0] * b1[0], p3 = a1[1] * b1[1];
                union { h2v h2[4]; h8 v; } uva, uvb, uss, uab;
                uva.h2[0] = __builtin_amdgcn_cvt_pkrtz(a0[0].x, a0[0].y);
                uva.h2[1] = __builtin_amdgcn_cvt_pkrtz(a0[1].x, a0[1].y);
                uva.h2[2] = __builtin_amdgcn_cvt_pkrtz(a1[0].x, a1[0].y);
                uva.h2[3] = __builtin_amdgcn_cvt_pkrtz(a1[1].x, a1[1].y);
                uvb.h2[0] = __builtin_amdgcn_cvt_pkrtz(b0[0].x, b0[0].y);
                uvb.h2[1] = __builtin_amdgcn_cvt_pkrtz(b0[1].x, b0[1].y);
                uvb.h2[2] = __builtin_amdgcn_cvt_pkrtz(b1[0].x, b1[0].y);
                uvb.h2[3] = __builtin_amdgcn_cvt_pkrtz(b1[1].x, b1[1].y);
                uss.h2[0] = __builtin_amdgcn_cvt_pkrtz(s0.x, s0.y);
                uss.h2[1] = __builtin_amdgcn_cvt_pkrtz(s1.x, s1.y);
                uss.h2[2] = __builtin_amdgcn_cvt_pkrtz(s2.x, s2.y);
                uss.h2[3] = __builtin_amdgcn_cvt_pkrtz(s3.x, s3.y);
                uab.h2[0] = __builtin_amdgcn_cvt_pkrtz(p0.x, p0.y);
                uab.h2[1] = __builtin_amdgcn_cvt_pkrtz(p1.x, p1.y);
                uab.h2[2] = __builtin_amdgcn_cvt_pkrtz(p2.x, p2.y);
                uab.h2[3] = __builtin_amdgcn_cvt_pkrtz(p3.x, p3.y);
                const int o = r * XP + c8 * 8;  // 16B-aligned
                *(h8*)&smem[0 * XQS + o] = uva.v;
                *(h8*)&smem[1 * XQS + o] = uvb.v;
                *(h8*)&smem[2 * XQS + o] = uss.v;
                *(h8*)&smem[3 * XQS + o] = uab.v;
            }
        }
        __syncthreads();                        // X ready

        // ---- prefetch next tile (overlaps h-conv; drained at next barrier) ----
        if (iter < ITERS - 1) {
            srp += PSTEP; hrp += PSTEP;
#pragma unroll
            for (int t = 0; t < 3; ++t) {
                if (okm & (1u << t)) {
                    const float4* pa = (const float4*)&srp[off[t]];
                    const float4* pb = (const float4*)&hrp[off[t]];
                    La0[t] = pa[0]; La1[t] = pa[1];
                    Lb0[t] = pb[0]; Lb1[t] = pb[1];
                }
            }
        }

        // ---- h-conv MFMA: wave w owns out-col tile w; A at k-offset 16w ----
        f32x4 acc[4][3] = {};                   // [plane][M-tile of h-rows]
#pragma unroll
        for (int Mt = 0; Mt < 3; ++Mt) {
            const int arow = (16 * Mt + l15) * XP + 16 * w + grp8;
#pragma unroll
            for (int q = 0; q < 4; ++q) {
                const h8 af = *(const h8*)&smem[q * XQS + arow];
                acc[q][Mt] = __builtin_amdgcn_mfma_f32_16x16x32_f16(af, bh, acc[q][Mt], 0, 0, 0);
            }
        }
        __syncthreads();                        // X consumed; reuse as Ht

        // ---- transpose-store D1 -> Ht[4][64][72] f16 ----
#pragma unroll
        for (int q = 0; q < 4; ++q) {
#pragma unroll
            for (int Mt = 0; Mt < 3; ++Mt) {
                union { h2v h2[2]; h4 v; } u;
                u.h2[0] = __builtin_amdgcn_cvt_pkrtz(acc[q][Mt][0], acc[q][Mt][1]);
                u.h2[1] = __builtin_amdgcn_cvt_pkrtz(acc[q][Mt][2], acc[q][Mt][3]);
                *(h4*)&smem[q * HTQS + (16 * w + l15) * HTP + 16 * Mt + grp4] = u.v;
            }
        }

        // ---- v-conv MFMA (wave-local Ht cols; no barrier needed before) ----
        f32x4 acc2[4][2] = {};
        const int abase = (16 * w + l15) * HTP + grp8;
#pragma unroll
        for (int q = 0; q < 4; ++q) {
            const h8 a0 = *(const h8*)&smem[q * HTQS + abase];       // rows 0-15
            const h8 a1 = *(const h8*)&smem[q * HTQS + abase + 16];  // rows 16-31
            acc2[q][0] = __builtin_amdgcn_mfma_f32_16x16x32_f16(a0, bv, acc2[q][0], 0, 0, 0);
            acc2[q][1] = __builtin_amdgcn_mfma_f32_16x16x32_f16(a1, bv, acc2[q][1], 0, 0, 0);
        }

        // ---- SSIM map on D2 fragments (8 px/thread) ----
#pragma unroll
        for (int nt = 0; nt < 2; ++nt) {
            const f32x4 m1 = acc2[0][nt] * rs;
            const f32x4 m2 = acc2[1][nt] * rs;
            const f32x4 S  = acc2[2][nt] * rs;   // E[a^2+b^2]
            const f32x4 pp = acc2[3][nt] * rs;   // E[ab]
            const f32x4 mu1s = m1 * m1, mu2s = m2 * m2, mu12 = m1 * m2;
            const f32x4 sg12 = pp - mu12;
            const f32x4 sgs  = S - mu1s - mu2s;  // sigma1^2 + sigma2^2
            const f32x4 num = (2.f * mu12 + C1) * (2.f * sg12 + C2);
            const f32x4 den = (mu1s + mu2s + C1) * (sgs + C2) + 1e-12f;
#pragma unroll
            for (int e = 0; e < 4; ++e)
                local += num[e] * __builtin_amdgcn_rcpf(den[e]);
        }
        __syncthreads();                        // Ht consumed before next X store
    }

    // ---- block reduction (once, amortized over 6 tiles) ----
#pragma unroll
    for (int offr = 32; offr > 0; offr >>= 1)
        local += __shfl_down(local, offr, 64);
    if ((tid & 63) == 0) wsums[tid >> 6] = local;
    __syncthreads();
    if (tid == 0) {
        const double bsum = (double)(wsums[0] + wsums[1] + wsums[2] + wsums[3]);
        if (mode == 0) {
            sink[blockIdx.x] = bsum;
        } else {
            atomicAdd(sink, bsum);
        }
    }
}

__global__ __launch_bounds__(256) void ssim_finalize(const double* __restrict__ partial,
                                                     float* __restrict__ out, int count) {
    __shared__ double ws[4];
    double s = 0.0;
    for (int i = threadIdx.x; i < count; i += 256) s += partial[i];
#pragma unroll
    for (int off = 32; off > 0; off >>= 1)
        s += __shfl_down(s, off, 64);
    const int lane = threadIdx.x & 63, wave = threadIdx.x >> 6;
    if (lane == 0) ws[wave] = s;
    __syncthreads();
    if (threadIdx.x == 0) {
        const double tot = ws[0] + ws[1] + ws[2] + ws[3];
        const double n = (double)NBC * IMG_H * IMG_W;
        out[0] = (float)(1.0 - tot / n);
    }
}

extern "C" void kernel_launch(void* const* d_in, const int* in_sizes, int n_in,
                              void* d_out, int out_size, void* d_ws, size_t ws_size,
                              hipStream_t stream) {
    const float* sr = (const float*)d_in[0];
    const float* hr = (const float*)d_in[1];
    float* out = (float*)d_out;

    if (ws_size >= (size_t)NPERS * sizeof(double)) {
        double* partial = (double*)d_ws; // fully overwritten each call
        ssim_main<<<dim3(NPERS), dim3(256), 0, stream>>>(sr, hr, partial, 0);
        ssim_finalize<<<dim3(1), dim3(256), 0, stream>>>(partial, out, NPERS);
    } else {
        double* acc = (double*)d_ws;
        ssim_init<<<dim3(1), dim3(64), 0, stream>>>(acc);
        ssim_main<<<dim3(NPERS), dim3(256), 0, stream>>>(sr, hr, acc, 1);
        ssim_finalize<<<dim3(1), dim3(256), 0, stream>>>(acc, out, 1);
    }
}

// Round 8
// 126.298 us; speedup vs baseline: 1.4323x; 1.0294x over previous
//
#include <hip/hip_runtime.h>

// SSIM loss, R11b: resubmission of R11 (bench was an infra failure —
// "MI355X container failed twice", 3rd occurrence; R1/R5 had the identical
// signature and passed unchanged on resubmit). BAR_LGKM re-audited: uniform
// barriers (6 iters for all blocks), compiler-generated ds ops ordered by
// "memory" clobber + lgkmcnt(0), prefetch consumed via register data-deps
// (compiler inserts vmcnt at use), all bounds guarded.
//
// R11 design. R10 post-mortem: prefetch was DEFEATED — VGPR_Count=64 proves
// the allocator sank the 48-reg prefetch below the 48-reg h-conv accumulators
// (schedule needed ~120 regs); and __syncthreads drains vmcnt(0) at every
// barrier anyway. R11 makes the overlap real:
//  - staging flattened to 480 tasks (48r x 10c8), 2 tasks/thread -> prefetch
//    footprint 32 VGPR; all waves share convert work evenly.
//  - prefetch pinned right after the X-ready barrier via sched_barrier(0);
//    __launch_bounds__(256,4) gives 128 VGPR budget (peak ~105).
//  - in-loop barriers = raw s_barrier + explicit lgkmcnt(0) ONLY (8-phase
//    template pattern): LDS ordering preserved, vmcnt NEVER drained at a
//    barrier -> prefetched loads stay in flight until next iter's convert.
// Unchanged: persistent 1024 blocks x 6 tiles (stride 8 BC planes), 4 planes
// (a,b,a2+b2,ab), one-k-step band MFMA h/v-conv, XP=104/HTP=72 alias layout,
// LDS g-table, rs compensation.

typedef __attribute__((ext_vector_type(2))) float  f32x2;
typedef __attribute__((ext_vector_type(4))) float  f32x4;
typedef __fp16 f16;
typedef __attribute__((ext_vector_type(2))) __fp16 h2v;
typedef __attribute__((ext_vector_type(4))) __fp16 h4;
typedef __attribute__((ext_vector_type(8))) __fp16 h8;

constexpr int IMG_H = 512;
constexpr int IMG_W = 512;
constexpr int PL    = IMG_H * IMG_W;
constexpr int NBC   = 48;
constexpr int TW    = 64;
constexpr int TH    = 32;
constexpr int NBLKX = IMG_W / TW;          // 8
constexpr int NBLKY = IMG_H / TH;          // 16
constexpr int NPERS = 1024;                // persistent blocks (4/CU)

constexpr int XP   = 104;                  // X pitch (halves)
constexpr int XR   = 48;                   // X rows (42 data + 6 zero pad)
constexpr int XQS  = XR * XP;              // 4992 halves per plane
constexpr int HTP  = 72;                   // Ht pitch (halves)
constexpr int HTQS = 64 * HTP;             // 4608 halves per plane
constexpr int SMEMH = 4 * XQS;             // 19968 halves = 39,936 B
static_assert(4 * HTQS <= SMEMH, "Ht must fit in X union");

constexpr float C1 = 1.0e-4f;
constexpr float C2 = 9.0e-4f;

// Raw barrier with LDS-only drain: orders all prior ds ops across the block
// WITHOUT forcing vmcnt (global prefetch stays in flight).
#define BAR_LGKM() do {                                       \
    __builtin_amdgcn_sched_barrier(0);                        \
    asm volatile("s_waitcnt lgkmcnt(0)" ::: "memory");        \
    __builtin_amdgcn_s_barrier();                             \
    __builtin_amdgcn_sched_barrier(0);                        \
} while (0)

// Normalized gaussian g[d] = exp(-(d-5)^2/4.5)/sum, f32-rounded.
__device__ const float GW[11] = {
    0.00102838f, 0.00759876f, 0.03600077f, 0.10936070f, 0.21300553f,
    0.26601172f, 0.21300553f, 0.10936070f, 0.03600077f, 0.00759876f,
    0.00102838f};

__device__ __forceinline__ h8 ldfrag(const f16* __restrict__ gtab, int base) {
    h8 b;
#pragma unroll
    for (int i = 0; i < 8; ++i) b[i] = gtab[base + i];
    return b;
}

// Convert one staging task (8 cols x 2 images) into the 4 quantity planes and
// store as 4x ds_write_b128.
__device__ __forceinline__ void cvt_store(f16* __restrict__ smem, int o,
                                          const float4& a0f, const float4& a1f,
                                          const float4& b0f, const float4& b1f) {
    const f32x2* a0 = (const f32x2*)&a0f;
    const f32x2* a1 = (const f32x2*)&a1f;
    const f32x2* b0 = (const f32x2*)&b0f;
    const f32x2* b1 = (const f32x2*)&b1f;
    const f32x2 s0 = a0[0] * a0[0] + b0[0] * b0[0];
    const f32x2 s1 = a0[1] * a0[1] + b0[1] * b0[1];
    const f32x2 s2 = a1[0] * a1[0] + b1[0] * b1[0];
    const f32x2 s3 = a1[1] * a1[1] + b1[1] * b1[1];
    const f32x2 p0 = a0[0] * b0[0], p1 = a0[1] * b0[1];
    const f32x2 p2 = a1[0] * b1[0], p3 = a1[1] * b1[1];
    union { h2v h2[4]; h8 v; } uva, uvb, uss, uab;
    uva.h2[0] = __builtin_amdgcn_cvt_pkrtz(a0[0].x, a0[0].y);
    uva.h2[1] = __builtin_amdgcn_cvt_pkrtz(a0[1].x, a0[1].y);
    uva.h2[2] = __builtin_amdgcn_cvt_pkrtz(a1[0].x, a1[0].y);
    uva.h2[3] = __builtin_amdgcn_cvt_pkrtz(a1[1].x, a1[1].y);
    uvb.h2[0] = __builtin_amdgcn_cvt_pkrtz(b0[0].x, b0[0].y);
    uvb.h2[1] = __builtin_amdgcn_cvt_pkrtz(b0[1].x, b0[1].y);
    uvb.h2[2] = __builtin_amdgcn_cvt_pkrtz(b1[0].x, b1[0].y);
    uvb.h2[3] = __builtin_amdgcn_cvt_pkrtz(b1[1].x, b1[1].y);
    uss.h2[0] = __builtin_amdgcn_cvt_pkrtz(s0.x, s0.y);
    uss.h2[1] = __builtin_amdgcn_cvt_pkrtz(s1.x, s1.y);
    uss.h2[2] = __builtin_amdgcn_cvt_pkrtz(s2.x, s2.y);
    uss.h2[3] = __builtin_amdgcn_cvt_pkrtz(s3.x, s3.y);
    uab.h2[0] = __builtin_amdgcn_cvt_pkrtz(p0.x, p0.y);
    uab.h2[1] = __builtin_amdgcn_cvt_pkrtz(p1.x, p1.y);
    uab.h2[2] = __builtin_amdgcn_cvt_pkrtz(p2.x, p2.y);
    uab.h2[3] = __builtin_amdgcn_cvt_pkrtz(p3.x, p3.y);
    *(h8*)&smem[0 * XQS + o] = uva.v;
    *(h8*)&smem[1 * XQS + o] = uvb.v;
    *(h8*)&smem[2 * XQS + o] = uss.v;
    *(h8*)&smem[3 * XQS + o] = uab.v;
}

__global__ __launch_bounds__(64) void ssim_init(double* acc) {
    if (threadIdx.x == 0) acc[0] = 0.0;
}

__global__ __launch_bounds__(256, 4) void ssim_main(const float* __restrict__ sr,
                                                    const float* __restrict__ hr,
                                                    double* __restrict__ sink,
                                                    int mode) {
    __shared__ __align__(16) f16 smem[SMEMH];   // X[4][48][104] / Ht[4][64][72] alias
    __shared__ __align__(8)  f16 gtab[128];     // zero-padded weights, g at [66..76]
    __shared__ float wsums[4];

    const int tid  = threadIdx.x;
    const int w    = tid >> 6;
    const int lane = tid & 63;
    const int l15  = lane & 15;
    const int grp8 = (lane >> 4) << 3;
    const int grp4 = (lane >> 4) << 2;

    // tile (x,y) fixed; BC plane steps by 8 per iteration
    const int bx  = blockIdx.x & 7;
    const int by  = (blockIdx.x >> 3) & 15;
    const int bc0 = blockIdx.x >> 7;            // 0..7
    const int gr0 = by * TH - 5;
    const int gc0 = bx * TW - 8;

    const float* __restrict__ srp = sr + (size_t)bc0 * PL;
    const float* __restrict__ hrp = hr + (size_t)bc0 * PL;
    const size_t PSTEP = (size_t)8 * PL;

    // ---- loop-invariant staging geometry: 480 tasks = 48 rows x 10 chunks ----
    const int tt0 = tid;                        // task 0 (always)
    const int tt1 = tid + 256;                  // task 1 (tid < 224)
    const bool t1v = (tid < 224);
    const int r_0 = tt0 / 10, c_0 = tt0 - 10 * r_0;
    const int r_1 = tt1 / 10, c_1 = tt1 - 10 * r_1;
    const int gr_0 = gr0 + r_0, gc_0 = gc0 + c_0 * 8;
    const int gr_1 = gr0 + r_1, gc_1 = gc0 + c_1 * 8;
    const bool ok0 = (r_0 < 42) & ((unsigned)gr_0 < (unsigned)IMG_H) &
                     ((unsigned)gc_0 < (unsigned)IMG_W);
    const bool ok1 = t1v & (r_1 < 42) & ((unsigned)gr_1 < (unsigned)IMG_H) &
                     ((unsigned)gc_1 < (unsigned)IMG_W);
    const int off0 = gr_0 * IMG_W + gc_0;
    const int off1 = gr_1 * IMG_W + gc_1;
    const int o0 = r_0 * XP + c_0 * 8;          // 16B-aligned store slots
    const int o1 = r_1 * XP + c_1 * 8;

    // ---- g-table fill ----
    if (tid < 128) {
        const int d = tid - 66;
        float v = 0.f;
        if ((unsigned)d <= 10u) v = GW[d];
        gtab[tid] = (f16)v;
    }

    // ---- rs compensation (pure-constant f16 round-trip) ----
    float s16 = 0.f;
#pragma unroll
    for (int d = 0; d <= 10; ++d) s16 += (float)(f16)GW[d];
    const float rs = 1.0f / (s16 * s16);

    // ---- prologue: zero task regs, load tile 0 ----
    float4 A0[2], A1[2], B0[2], B1[2];          // 32 VGPR prefetch footprint
#pragma unroll
    for (int t = 0; t < 2; ++t)
        A0[t] = A1[t] = B0[t] = B1[t] = (float4){0.f, 0.f, 0.f, 0.f};
    if (ok0) {
        const float4* pa = (const float4*)&srp[off0];
        const float4* pb = (const float4*)&hrp[off0];
        A0[0] = pa[0]; A1[0] = pa[1]; B0[0] = pb[0]; B1[0] = pb[1];
    }
    if (ok1) {
        const float4* pa = (const float4*)&srp[off1];
        const float4* pb = (const float4*)&hrp[off1];
        A0[1] = pa[0]; A1[1] = pa[1]; B0[1] = pb[0]; B1[1] = pb[1];
    }
    __syncthreads();                            // gtab ready (full drain OK here)

    // ---- loop-invariant B fragments ----
    const h8 bh = ldfrag(gtab, 63 + grp8 - l15);   // h-conv: g[kl-l15-3]
    const h8 bv = ldfrag(gtab, 66 + grp8 - l15);   // v-conv: g[kl-l15]

    float local = 0.f;

    for (int bc = bc0; bc < NBC; bc += 8) {
        // ---- A: convert + store X (2 tasks; rows>=42 store zeros = pad) ----
        cvt_store(smem, o0, A0[0], A1[0], B0[0], B1[0]);
        if (t1v) cvt_store(smem, o1, A0[1], A1[1], B0[1], B1[1]);

        BAR_LGKM();                             // X ready (no vmcnt drain)

        // ---- prefetch next tile: pinned here; stays in flight across all
        //      following barriers, consumed at next iter's phase A ----
        if (bc + 8 < NBC) {
            srp += PSTEP; hrp += PSTEP;
            if (ok0) {
                const float4* pa = (const float4*)&srp[off0];
                const float4* pb = (const float4*)&hrp[off0];
                A0[0] = pa[0]; A1[0] = pa[1]; B0[0] = pb[0]; B1[0] = pb[1];
            }
            if (ok1) {
                const float4* pa = (const float4*)&srp[off1];
                const float4* pb = (const float4*)&hrp[off1];
                A0[1] = pa[0]; A1[1] = pa[1]; B0[1] = pb[0]; B1[1] = pb[1];
            }
        }
        __builtin_amdgcn_sched_barrier(0);      // pin issue before h-conv

        // ---- h-conv MFMA: wave w owns out-col tile w; A at k-offset 16w ----
        f32x4 acc[4][3] = {};
#pragma unroll
        for (int Mt = 0; Mt < 3; ++Mt) {
            const int arow = (16 * Mt + l15) * XP + 16 * w + grp8;
#pragma unroll
            for (int q = 0; q < 4; ++q) {
                const h8 af = *(const h8*)&smem[q * XQS + arow];
                acc[q][Mt] = __builtin_amdgcn_mfma_f32_16x16x32_f16(af, bh, acc[q][Mt], 0, 0, 0);
            }
        }

        BAR_LGKM();                             // X consumed; reuse as Ht

        // ---- transpose-store D1 -> Ht[4][64][72] f16 ----
#pragma unroll
        for (int q = 0; q < 4; ++q) {
#pragma unroll
            for (int Mt = 0; Mt < 3; ++Mt) {
                union { h2v h2[2]; h4 v; } u;
                u.h2[0] = __builtin_amdgcn_cvt_pkrtz(acc[q][Mt][0], acc[q][Mt][1]);
                u.h2[1] = __builtin_amdgcn_cvt_pkrtz(acc[q][Mt][2], acc[q][Mt][3]);
                *(h4*)&smem[q * HTQS + (16 * w + l15) * HTP + 16 * Mt + grp4] = u.v;
            }
        }

        // ---- v-conv MFMA (wave-own Ht cols; same-wave RAW auto-ordered) ----
        f32x4 acc2[4][2] = {};
        const int abase = (16 * w + l15) * HTP + grp8;
#pragma unroll
        for (int q = 0; q < 4; ++q) {
            const h8 a0 = *(const h8*)&smem[q * HTQS + abase];
            const h8 a1 = *(const h8*)&smem[q * HTQS + abase + 16];
            acc2[q][0] = __builtin_amdgcn_mfma_f32_16x16x32_f16(a0, bv, acc2[q][0], 0, 0, 0);
            acc2[q][1] = __builtin_amdgcn_mfma_f32_16x16x32_f16(a1, bv, acc2[q][1], 0, 0, 0);
        }

        // ---- SSIM map on D2 fragments (8 px/thread) ----
#pragma unroll
        for (int nt = 0; nt < 2; ++nt) {
            const f32x4 m1 = acc2[0][nt] * rs;
            const f32x4 m2 = acc2[1][nt] * rs;
            const f32x4 S  = acc2[2][nt] * rs;
            const f32x4 pp = acc2[3][nt] * rs;
            const f32x4 mu1s = m1 * m1, mu2s = m2 * m2, mu12 = m1 * m2;
            const f32x4 sg12 = pp - mu12;
            const f32x4 sgs  = S - mu1s - mu2s;
            const f32x4 num = (2.f * mu12 + C1) * (2.f * sg12 + C2);
            const f32x4 den = (mu1s + mu2s + C1) * (sgs + C2) + 1e-12f;
#pragma unroll
            for (int e = 0; e < 4; ++e)
                local += num[e] * __builtin_amdgcn_rcpf(den[e]);
        }

        BAR_LGKM();                             // Ht consumed before next X store
    }

    // ---- block reduction ----
#pragma unroll
    for (int offr = 32; offr > 0; offr >>= 1)
        local += __shfl_down(local, offr, 64);
    if ((tid & 63) == 0) wsums[tid >> 6] = local;
    __syncthreads();
    if (tid == 0) {
        const double bsum = (double)(wsums[0] + wsums[1] + wsums[2] + wsums[3]);
        if (mode == 0) {
            sink[blockIdx.x] = bsum;
        } else {
            atomicAdd(sink, bsum);
        }
    }
}

__global__ __launch_bounds__(256) void ssim_finalize(const double* __restrict__ partial,
                                                     float* __restrict__ out, int count) {
    __shared__ double ws[4];
    double s = 0.0;
    for (int i = threadIdx.x; i < count; i += 256) s += partial[i];
#pragma unroll
    for (int off = 32; off > 0; off >>= 1)
        s += __shfl_down(s, off, 64);
    const int lane = threadIdx.x & 63, wave = threadIdx.x >> 6;
    if (lane == 0) ws[wave] = s;
    __syncthreads();
    if (threadIdx.x == 0) {
        const double tot = ws[0] + ws[1] + ws[2] + ws[3];
        const double n = (double)NBC * IMG_H * IMG_W;
        out[0] = (float)(1.0 - tot / n);
    }
}

extern "C" void kernel_launch(void* const* d_in, const int* in_sizes, int n_in,
                              void* d_out, int out_size, void* d_ws, size_t ws_size,
                              hipStream_t stream) {
    const float* sr = (const float*)d_in[0];
    const float* hr = (const float*)d_in[1];
    float* out = (float*)d_out;

    if (ws_size >= (size_t)NPERS * sizeof(double)) {
        double* partial = (double*)d_ws; // fully overwritten each call
        ssim_main<<<dim3(NPERS), dim3(256), 0, stream>>>(sr, hr, partial, 0);
        ssim_finalize<<<dim3(1), dim3(256), 0, stream>>>(partial, out, NPERS);
    } else {
        double* acc = (double*)d_ws;
        ssim_init<<<dim3(1), dim3(64), 0, stream>>>(acc);
        ssim_main<<<dim3(NPERS), dim3(256), 0, stream>>>(sr, hr, acc, 1);
        ssim_finalize<<<dim3(1), dim3(256), 0, stream>>>(acc, out, 1);
    }
}